// Round 10
// baseline (356.639 us; speedup 1.0000x reference)
//
#include <hip/hip_runtime.h>
#include <hip/hip_bf16.h>
#include <string.h>

// B=8, N=16384 (H=W=128), D=128, WS=4 -> nW=1024, P=16 tok/window, NH=2, dh=64.
// Two fused kernels (K1: LN1+W-MSA+res1+LN2+MLP1; K2: LN3+SW-MSA+res2+LN4+MLP2).
// Block = 64 tokens (4 windows), 512 threads (8 waves), LDS 80K -> 2 blocks/CU.

typedef unsigned short u16;
typedef unsigned int   u32;
typedef __attribute__((ext_vector_type(8))) short bf16x8;
typedef __attribute__((ext_vector_type(4))) float f32x4;

#define MFMA(a,b,c) __builtin_amdgcn_mfma_f32_16x16x32_bf16(a,b,c,0,0,0)

// compiler-generated v_cvt_bf16_f32 / v_cvt_pk_bf16_f32 (RNE) — not hand-rolled.
// (__hip_bfloat16 isn't trivially copyable on this ROCm -> memcpy, not bit_cast.)
__device__ __forceinline__ u16 f2bf(float x) {
    __hip_bfloat16 h = __float2bfloat16(x);
    u16 r; memcpy(&r, &h, 2); return r;
}
__device__ __forceinline__ u32 pack2(float lo, float hi) {
    __hip_bfloat162 h = __float22bfloat162_rn(make_float2(lo, hi));
    u32 r; memcpy(&r, &h, 4); return r;
}
// tanh-form GELU via hw exp2 + rcp. |err| vs exact erf-GELU < ~1e-3.
__device__ __forceinline__ float gelu_fast(float x) {
    float t = x * fmaf(x * x, 0.044715f, 1.0f);
    float e = __builtin_amdgcn_exp2f(-2.3022078f * t);
    return x * __builtin_amdgcn_rcpf(1.0f + e);
}
__device__ __forceinline__ bf16x8 ldsfrag(const u16* base, int byte) {
    return *(const bf16x8*)((const char*)base + byte);
}
__device__ __forceinline__ bf16x8 ldg8(const u16* __restrict__ p) {
    return *(const bf16x8*)p;
}
// wg in [0,256): group of 4 windows; tok in [0,64).
template <int BRANCH>
__device__ __forceinline__ int src_index(int wg, int tok) {
    int win = (wg << 2) + (tok >> 4), p = tok & 15;
    int r = ((win >> 5) << 2) | (p >> 2);
    int c = ((win & 31) << 2) | (p & 3);
    if (BRANCH == 1) return (r << 7) | c;
    int r2 = (r + 2) & 127, c2 = (c + 2) & 127;
    return ((((r2 >> 2) << 5) | (c2 >> 2)) << 4) | ((r2 & 3) << 2) | (c2 & 3);
}

// ---------------------------------------------------------------------------
// Weight fp32 -> bf16 prep.
// ---------------------------------------------------------------------------
__global__ __launch_bounds__(256)
void cvt_weights(const float* __restrict__ qkv1, const float* __restrict__ o1,
                 const float* __restrict__ w11,  const float* __restrict__ w12,
                 const float* __restrict__ qkv2, const float* __restrict__ o2,
                 const float* __restrict__ w21,  const float* __restrict__ w22,
                 u16* __restrict__ dst)
{
    int e = (blockIdx.x * 256 + threadIdx.x) * 8;
    const float* src; int off;
    if      (e < 49152)  { src = qkv1; off = 0; }
    else if (e < 65536)  { src = o1;   off = 49152; }
    else if (e < 131072) { src = w11;  off = 65536; }
    else if (e < 196608) { src = w12;  off = 131072; }
    else if (e < 245760) { src = qkv2; off = 196608; }
    else if (e < 262144) { src = o2;   off = 245760; }
    else if (e < 327680) { src = w21;  off = 262144; }
    else                 { src = w22;  off = 327680; }
    float4 a = *(const float4*)(src + (e - off));
    float4 b = *(const float4*)(src + (e - off) + 4);
    uint4 o;
    o.x = pack2(a.x, a.y); o.y = pack2(a.z, a.w);
    o.z = pack2(b.x, b.y); o.w = pack2(b.z, b.w);
    *(uint4*)(dst + e) = o;
}

// ---------------------------------------------------------------------------
// Fused half-block: LN_A + windowed MHSA + residual(LDS) + LN_B + MLP.
// LDS (81920 B = exactly 2 blocks/CU):
//   xs[64][256B]@0 | qls[64][256B]@16K | kls[64][256B]@32K | vt[128][256B]@48K
//   (vt: data bytes 0..127, zero pad 128..255; PV reads for win=3/q4>=2 land
//    in the zeroed pad and multiply P's zero K-pad).
// Overlays: resf fp32 [64][512B] = qls+kls; P[64][128B] = qls;
//           h1a = vt@48K, h1b = vt@64K (16K each, double-buffered MLP hidden).
// ---------------------------------------------------------------------------
template <int BRANCH>
__global__ __launch_bounds__(512, 4)
void swin_fused(const float* __restrict__ xin,   // LN_A source
                const float* __restrict__ resin, // residual source
                float* __restrict__ resout,      // output
                const float* __restrict__ lnA_g, const float* __restrict__ lnA_b,
                const float* __restrict__ lnB_g, const float* __restrict__ lnB_b,
                const u16* __restrict__ qkvw, const float* __restrict__ qkvb,
                const u16* __restrict__ ow,   const float* __restrict__ ob,
                const u16* __restrict__ w1,   const float* __restrict__ b1,
                const u16* __restrict__ w2,   const float* __restrict__ b2)
{
    __shared__ __align__(16) char smem[81920];
    u16*   xs   = (u16*)smem;
    u16*   qls  = (u16*)(smem + 16384);
    u16*   kls  = (u16*)(smem + 32768);
    u16*   vt   = (u16*)(smem + 49152);
    float* resf = (float*)(smem + 16384);
    u16*   h1a  = (u16*)(smem + 49152);
    u16*   h1b  = (u16*)(smem + 65536);

    const int t  = threadIdx.x;
    const int wv = t >> 6, ln = t & 63, l15 = ln & 15, q4 = ln >> 4;
    const int bb = blockIdx.x >> 8, wg = blockIdx.x & 255;
    const int xa = (l15 & 7) << 4;
    const size_t gbase = (size_t)bb * 16384;

    // ---------- phase 0: gather + LN_A -> xs (bf16); zero vt pad ----------
    {
        int token = t >> 3, part = t & 7;               // 8 thr/token, 16 dims each
        int nsrc = src_index<BRANCH>(wg, token);
        const float* src = xin + (gbase + nsrc) * 128;
        float v[16];
#pragma unroll
        for (int j = 0; j < 4; ++j)
            *(float4*)&v[j * 4] = *(const float4*)(src + part * 4 + 32 * j);
        float s = 0.f, s2 = 0.f;
#pragma unroll
        for (int i = 0; i < 16; ++i) { s += v[i]; s2 += v[i] * v[i]; }
        s  += __shfl_xor(s, 1, 8);  s  += __shfl_xor(s, 2, 8);  s  += __shfl_xor(s, 4, 8);
        s2 += __shfl_xor(s2, 1, 8); s2 += __shfl_xor(s2, 2, 8); s2 += __shfl_xor(s2, 4, 8);
        float mu = s * (1.f / 128.f);
        float rstd = rsqrtf(s2 * (1.f / 128.f) - mu * mu + 1e-5f);
        int xk = (token & 7) << 4;
#pragma unroll
        for (int j = 0; j < 4; ++j) {
            int d0 = part * 4 + 32 * j;
            float a0 = (v[j * 4 + 0] - mu) * rstd * lnA_g[d0]     + lnA_b[d0];
            float a1 = (v[j * 4 + 1] - mu) * rstd * lnA_g[d0 + 1] + lnA_b[d0 + 1];
            float a2 = (v[j * 4 + 2] - mu) * rstd * lnA_g[d0 + 2] + lnA_b[d0 + 2];
            float a3 = (v[j * 4 + 3] - mu) * rstd * lnA_g[d0 + 3] + lnA_b[d0 + 3];
            int byte = token * 256 + ((part * 8 + j * 64) ^ xk);
            *(uint2*)((char*)xs + byte) = make_uint2(pack2(a0, a1), pack2(a2, a3));
        }
        // zero vt pad: all 128 rows, bytes [128,256)
        int row = t >> 2, base = row * 256 + 128 + (t & 3) * 32;
        uint4 z = {0, 0, 0, 0};
        *(uint4*)((char*)vt + base)      = z;
        *(uint4*)((char*)vt + base + 16) = z;
    }
    __syncthreads();

    // ---------- phase 1: QKV GEMM (M=64, N=384, K=128) ----------
#pragma unroll 1
    for (int i = 0; i < 3; ++i) {
        int n0 = (wv * 3 + i) * 16;
        int part = n0 >> 7, c0 = n0 & 127;
        bf16x8 wf[4];
#pragma unroll
        for (int kf = 0; kf < 4; ++kf)
            wf[kf] = ldg8(qkvw + (size_t)(n0 + l15) * 128 + kf * 32 + q4 * 8);
        float bias = qkvb[n0 + l15];
        f32x4 acc[4];
#pragma unroll
        for (int mf = 0; mf < 4; ++mf) acc[mf] = (f32x4){bias, bias, bias, bias};
#pragma unroll
        for (int kf = 0; kf < 4; ++kf)
#pragma unroll
            for (int mf = 0; mf < 4; ++mf) {
                bf16x8 afr = ldsfrag(xs, (mf * 16 + l15) * 256 + ((kf * 64 + q4 * 16) ^ xa));
                acc[mf] = MFMA(afr, wf[kf], acc[mf]);
            }
        if (part < 2) {                       // q (scaled) / k, token-major
            u16* dst = part ? kls : qls;
            float sc = part ? 1.f : 0.125f;
#pragma unroll
            for (int mf = 0; mf < 4; ++mf)
#pragma unroll
                for (int r = 0; r < 4; ++r) {
                    int tok = mf * 16 + q4 * 4 + r;
                    int byte = tok * 256 + ((2 * (c0 + l15)) ^ ((tok & 7) << 4));
                    dst[byte >> 1] = f2bf(acc[mf][r] * sc);
                }
        } else {                              // v -> vt[dh][tok], 256B stride
            int dh = c0 + l15, xr = (dh & 7) << 4;
#pragma unroll
            for (int mf = 0; mf < 4; ++mf) {
                int tok0 = mf * 16 + q4 * 4;
                u32 lo = pack2(acc[mf][0], acc[mf][1]);
                u32 hi = pack2(acc[mf][2], acc[mf][3]);
                int byte = dh * 256 + ((2 * tok0) ^ xr);
                *(uint2*)((char*)vt + byte) = make_uint2(lo, hi);
            }
        }
    }
    __syncthreads();

    // ---------- phase 2: scores. 1 (window,head) pair per wave ----------
    f32x4 S;
    {
        int win = wv >> 1, h = wv & 1;
        f32x4 z = {0.f, 0.f, 0.f, 0.f};
        int tok = win * 16 + l15, xk = (tok & 7) << 4;
#pragma unroll
        for (int kf = 0; kf < 2; ++kf) {
            int byte = tok * 256 + ((h * 128 + kf * 64 + q4 * 16) ^ xk);
            bf16x8 aq = ldsfrag(qls, byte);
            bf16x8 bk = ldsfrag(kls, byte);
            z = MFMA(aq, bk, z);
        }
        S = z;
    }
    __syncthreads();   // q reads done before P overlays qls

    // ---------- softmax in-register; P (bf16, K padded to 32) -> qls ----------
    {
        int win = wv >> 1, h = wv & 1;
#pragma unroll
        for (int r = 0; r < 4; ++r) {
            float v = S[r];
            float m = v;
            m = fmaxf(m, __shfl_xor(m, 1, 16)); m = fmaxf(m, __shfl_xor(m, 2, 16));
            m = fmaxf(m, __shfl_xor(m, 4, 16)); m = fmaxf(m, __shfl_xor(m, 8, 16));
            float e = __builtin_amdgcn_exp2f((v - m) * 1.44269504f);
            float sm = e;
            sm += __shfl_xor(sm, 1, 16); sm += __shfl_xor(sm, 2, 16);
            sm += __shfl_xor(sm, 4, 16); sm += __shfl_xor(sm, 8, 16);
            float p = e * __builtin_amdgcn_rcpf(sm);
            int tok = win * 16 + q4 * 4 + r, xk = (tok & 7) << 4;
            qls[(tok * 128 + ((h * 64 + l15 * 2)      ^ xk)) >> 1] = f2bf(p);
            qls[(tok * 128 + ((h * 64 + 32 + l15 * 2) ^ xk)) >> 1] = 0;
        }
    }
    __syncthreads();

    // ---------- phase 3: PV -> xs (attn-out bf16) ----------
    {
        int win = wv >> 1, h = wv & 1;
        int atok = win * 16 + l15;
        bf16x8 ap = ldsfrag(qls, atok * 128 + ((h * 64 + q4 * 16) ^ ((atok & 7) << 4)));
#pragma unroll
        for (int nf = 0; nf < 4; ++nf) {
            int dh = h * 64 + nf * 16 + l15;
            bf16x8 bv = ldsfrag(vt, dh * 256 + ((win * 32 + q4 * 16) ^ ((dh & 7) << 4)));
            f32x4 z = {0.f, 0.f, 0.f, 0.f};
            f32x4 o = MFMA(ap, bv, z);
#pragma unroll
            for (int r = 0; r < 4; ++r) {
                int tok = win * 16 + q4 * 4 + r;
                xs[(tok * 256 + ((2 * dh) ^ ((tok & 7) << 4))) >> 1] = f2bf(o[r]);
            }
        }
    }
    __syncthreads();

    // ---------- phase 4: output projection + residual -> resf (LDS fp32) ----------
    {
        int n0 = wv * 16;
        bf16x8 wf[4];
#pragma unroll
        for (int kf = 0; kf < 4; ++kf)
            wf[kf] = ldg8(ow + (size_t)(n0 + l15) * 128 + kf * 32 + q4 * 8);
        float bias = ob[n0 + l15];
        f32x4 acc[4];
#pragma unroll
        for (int mf = 0; mf < 4; ++mf) acc[mf] = (f32x4){bias, bias, bias, bias};
#pragma unroll
        for (int kf = 0; kf < 4; ++kf)
#pragma unroll
            for (int mf = 0; mf < 4; ++mf) {
                bf16x8 afr = ldsfrag(xs, (mf * 16 + l15) * 256 + ((kf * 64 + q4 * 16) ^ xa));
                acc[mf] = MFMA(afr, wf[kf], acc[mf]);
            }
#pragma unroll
        for (int mf = 0; mf < 4; ++mf)
#pragma unroll
            for (int r = 0; r < 4; ++r) {
                int tok = mf * 16 + q4 * 4 + r;
                int nd = (BRANCH == 1) ? (wg * 64 + tok) : src_index<2>(wg, tok);
                float rv = resin[(gbase + nd) * 128 + n0 + l15];
                if (BRANCH == 1) rv = truncf(rv);
                int byte = tok * 512 + ((4 * (n0 + l15)) ^ ((tok & 7) << 4));
                *(float*)((char*)resf + byte) = rv + acc[mf][r];
            }
    }
    __syncthreads();

    // ---------- phase 5: LN_B over resf -> xs (bf16) ----------
    // resf stores dim d of token at physical byte (4d)^xk (xk 16-aligned), so
    // reading physical chunk ((part*16+j*128)^xk) yields LOGICAL dims part*4+32j.
    {
        int token = t >> 3, part = t & 7;
        int xk = (token & 7) << 4;
        float v[16];
#pragma unroll
        for (int j = 0; j < 4; ++j)
            *(float4*)&v[j * 4] =
                *(const float4*)((char*)resf + token * 512 + ((part * 16 + j * 128) ^ xk));
        float s = 0.f, s2 = 0.f;
#pragma unroll
        for (int i = 0; i < 16; ++i) { s += v[i]; s2 += v[i] * v[i]; }
        s  += __shfl_xor(s, 1, 8);  s  += __shfl_xor(s, 2, 8);  s  += __shfl_xor(s, 4, 8);
        s2 += __shfl_xor(s2, 1, 8); s2 += __shfl_xor(s2, 2, 8); s2 += __shfl_xor(s2, 4, 8);
        float mu = s * (1.f / 128.f);
        float rstd = rsqrtf(s2 * (1.f / 128.f) - mu * mu + 1e-5f);
#pragma unroll
        for (int j = 0; j < 4; ++j) {
            int d0 = part * 4 + 32 * j;
            float a0 = (v[j * 4 + 0] - mu) * rstd * lnB_g[d0]     + lnB_b[d0];
            float a1 = (v[j * 4 + 1] - mu) * rstd * lnB_g[d0 + 1] + lnB_b[d0 + 1];
            float a2 = (v[j * 4 + 2] - mu) * rstd * lnB_g[d0 + 2] + lnB_b[d0 + 2];
            float a3 = (v[j * 4 + 3] - mu) * rstd * lnB_g[d0 + 3] + lnB_b[d0 + 3];
            int byte = token * 256 + ((part * 8 + j * 64) ^ xk);
            *(uint2*)((char*)xs + byte) = make_uint2(pack2(a0, a1), pack2(a2, a3));
        }
    }
    __syncthreads();

    // ---------- phase 6: MLP, 4 chunks x 128 h1-cols, double-buffered h1.
    //            G1(c) + G2(c-1) share a barrier region; weight frags preloaded.
    const int nm = wv * 16;
    f32x4 acc2[4];
    {
        float bias = b2[nm + l15];
#pragma unroll
        for (int mf = 0; mf < 4; ++mf) acc2[mf] = (f32x4){bias, bias, bias, bias};
    }
    // chunk 0: GEMM1 only
    {
        bf16x8 w1f[4];
#pragma unroll
        for (int kf = 0; kf < 4; ++kf)
            w1f[kf] = ldg8(w1 + (size_t)(nm + l15) * 128 + kf * 32 + q4 * 8);
        float bias = b1[nm + l15];
        f32x4 acc1[4];
#pragma unroll
        for (int mf = 0; mf < 4; ++mf) acc1[mf] = (f32x4){bias, bias, bias, bias};
#pragma unroll
        for (int kf = 0; kf < 4; ++kf)
#pragma unroll
            for (int mf = 0; mf < 4; ++mf) {
                bf16x8 afr = ldsfrag(xs, (mf * 16 + l15) * 256 + ((kf * 64 + q4 * 16) ^ xa));
                acc1[mf] = MFMA(afr, w1f[kf], acc1[mf]);
            }
#pragma unroll
        for (int mf = 0; mf < 4; ++mf)
#pragma unroll
            for (int r = 0; r < 4; ++r) {
                int tok = mf * 16 + q4 * 4 + r;
                h1a[(tok * 256 + ((2 * (nm + l15)) ^ ((tok & 7) << 4))) >> 1] =
                    f2bf(gelu_fast(acc1[mf][r]));
            }
    }
    __syncthreads();
#pragma unroll 1
    for (int c = 1; c < 4; ++c) {
        u16* hcur  = (c & 1) ? h1b : h1a;   // G1(c) store target
        u16* hprev = (c & 1) ? h1a : h1b;   // G2(c-1) source
        bf16x8 w1f[4], w2f[4];
#pragma unroll
        for (int kf = 0; kf < 4; ++kf)
            w1f[kf] = ldg8(w1 + (size_t)(c * 128 + nm + l15) * 128 + kf * 32 + q4 * 8);
#pragma unroll
        for (int kf = 0; kf < 4; ++kf)
            w2f[kf] = ldg8(w2 + (size_t)(nm + l15) * 512 + (c - 1) * 128 + kf * 32 + q4 * 8);
        // G2(c-1)
#pragma unroll
        for (int kf = 0; kf < 4; ++kf)
#pragma unroll
            for (int mf = 0; mf < 4; ++mf) {
                bf16x8 afr = ldsfrag(hprev, (mf * 16 + l15) * 256 + ((kf * 64 + q4 * 16) ^ xa));
                acc2[mf] = MFMA(afr, w2f[kf], acc2[mf]);
            }
        // G1(c)
        float bias = b1[c * 128 + nm + l15];
        f32x4 acc1[4];
#pragma unroll
        for (int mf = 0; mf < 4; ++mf) acc1[mf] = (f32x4){bias, bias, bias, bias};
#pragma unroll
        for (int kf = 0; kf < 4; ++kf)
#pragma unroll
            for (int mf = 0; mf < 4; ++mf) {
                bf16x8 afr = ldsfrag(xs, (mf * 16 + l15) * 256 + ((kf * 64 + q4 * 16) ^ xa));
                acc1[mf] = MFMA(afr, w1f[kf], acc1[mf]);
            }
#pragma unroll
        for (int mf = 0; mf < 4; ++mf)
#pragma unroll
            for (int r = 0; r < 4; ++r) {
                int tok = mf * 16 + q4 * 4 + r;
                hcur[(tok * 256 + ((2 * (nm + l15)) ^ ((tok & 7) << 4))) >> 1] =
                    f2bf(gelu_fast(acc1[mf][r]));
            }
        __syncthreads();
    }
    // tail: G2(3) from h1b
    {
        bf16x8 w2f[4];
#pragma unroll
        for (int kf = 0; kf < 4; ++kf)
            w2f[kf] = ldg8(w2 + (size_t)(nm + l15) * 512 + 384 + kf * 32 + q4 * 8);
#pragma unroll
        for (int kf = 0; kf < 4; ++kf)
#pragma unroll
            for (int mf = 0; mf < 4; ++mf) {
                bf16x8 afr = ldsfrag(h1b, (mf * 16 + l15) * 256 + ((kf * 64 + q4 * 16) ^ xa));
                acc2[mf] = MFMA(afr, w2f[kf], acc2[mf]);
            }
    }

    // ---------- phase 7: out = gelu(acc2) + resf -> global ----------
#pragma unroll
    for (int mf = 0; mf < 4; ++mf)
#pragma unroll
        for (int r = 0; r < 4; ++r) {
            int tok = mf * 16 + q4 * 4 + r;
            int nd = (BRANCH == 1) ? (wg * 64 + tok) : src_index<2>(wg, tok);
            float res = *(const float*)((char*)resf +
                            tok * 512 + ((4 * (nm + l15)) ^ ((tok & 7) << 4)));
            resout[(gbase + nd) * 128 + nm + l15] = gelu_fast(acc2[mf][r]) + res;
        }
}

extern "C" void kernel_launch(void* const* d_in, const int* in_sizes, int n_in,
                              void* d_out, int out_size, void* d_ws, size_t ws_size,
                              hipStream_t stream) {
    (void)in_sizes; (void)n_in; (void)out_size; (void)ws_size;
    const float* x      = (const float*)d_in[0];
    const float* ln1_g  = (const float*)d_in[1];
    const float* ln1_b  = (const float*)d_in[2];
    const float* ln2_g  = (const float*)d_in[3];
    const float* ln2_b  = (const float*)d_in[4];
    const float* ln3_g  = (const float*)d_in[5];
    const float* ln3_b  = (const float*)d_in[6];
    const float* ln4_g  = (const float*)d_in[7];
    const float* ln4_b  = (const float*)d_in[8];
    const float* qkv1_w = (const float*)d_in[9];
    const float* qkv1_b = (const float*)d_in[10];
    const float* out1_w = (const float*)d_in[11];
    const float* out1_b = (const float*)d_in[12];
    const float* qkv2_w = (const float*)d_in[13];
    const float* qkv2_b = (const float*)d_in[14];
    const float* out2_w = (const float*)d_in[15];
    const float* out2_b = (const float*)d_in[16];
    const float* mlp1_w1 = (const float*)d_in[17];
    const float* mlp1_b1 = (const float*)d_in[18];
    const float* mlp1_w2 = (const float*)d_in[19];
    const float* mlp1_b2 = (const float*)d_in[20];
    const float* mlp2_w1 = (const float*)d_in[21];
    const float* mlp2_b1 = (const float*)d_in[22];
    const float* mlp2_w2 = (const float*)d_in[23];
    const float* mlp2_b2 = (const float*)d_in[24];

    // bf16 weights in d_ws (786 KiB total)
    u16* wb = (u16*)d_ws;
    u16* qkv1bf = wb + 0;
    u16* out1bf = wb + 49152;
    u16* m1w1bf = wb + 65536;
    u16* m1w2bf = wb + 131072;
    u16* qkv2bf = wb + 196608;
    u16* out2bf = wb + 245760;
    u16* m2w1bf = wb + 262144;
    u16* m2w2bf = wb + 327680;

    float* out = (float*)d_out;

    cvt_weights<<<dim3(192), dim3(256), 0, stream>>>(
        qkv1_w, out1_w, mlp1_w1, mlp1_w2, qkv2_w, out2_w, mlp2_w1, mlp2_w2, wb);

    // K1: W-MSA + MLP1 -> out1 (writes every element of d_out)
    swin_fused<1><<<dim3(2048), dim3(512), 0, stream>>>(
        x, x, out,
        ln1_g, ln1_b, ln2_g, ln2_b,
        qkv1bf, qkv1_b, out1bf, out1_b,
        m1w1bf, mlp1_b1, m1w2bf, mlp1_b2);

    // K2: SW-MSA + MLP2 -> out2, in place (block gather set == scatter set)
    swin_fused<2><<<dim3(2048), dim3(512), 0, stream>>>(
        out, out, out,
        ln3_g, ln3_b, ln4_g, ln4_b,
        qkv2bf, qkv2_b, out2bf, out2_b,
        m2w1bf, mlp2_b1, m2w2bf, mlp2_b2);
}

// Round 11
// 325.790 us; speedup vs baseline: 1.0947x; 1.0947x over previous
//
#include <hip/hip_runtime.h>
#include <hip/hip_bf16.h>
#include <string.h>

// B=8, N=16384 (H=W=128), D=128, WS=4 -> nW=1024, P=16 tok/window, NH=2, dh=64.
// Two fused kernels (K1: LN1+W-MSA+res1+LN2+MLP1; K2: LN3+SW-MSA+res2+LN4+MLP2).
// Block = 64 tokens (4 windows), 512 threads (8 waves), LDS 80K -> 2 blocks/CU.
// NOTE: weight loads stay INLINE in MFMA loops — hand-hoisted frag arrays at the
// (512,4) 128-reg cap caused 160 MB of scratch spill (R10 WRITE_SIZE evidence).

typedef unsigned short u16;
typedef unsigned int   u32;
typedef __attribute__((ext_vector_type(8))) short bf16x8;
typedef __attribute__((ext_vector_type(4))) float f32x4;

#define MFMA(a,b,c) __builtin_amdgcn_mfma_f32_16x16x32_bf16(a,b,c,0,0,0)

// compiler-generated v_cvt_bf16_f32 / v_cvt_pk_bf16_f32 (RNE).
__device__ __forceinline__ u16 f2bf(float x) {
    __hip_bfloat16 h = __float2bfloat16(x);
    u16 r; memcpy(&r, &h, 2); return r;
}
__device__ __forceinline__ u32 pack2(float lo, float hi) {
    __hip_bfloat162 h = __float22bfloat162_rn(make_float2(lo, hi));
    u32 r; memcpy(&r, &h, 4); return r;
}
// tanh-form GELU via hw exp2 + rcp. |err| vs exact erf-GELU < ~1e-3.
__device__ __forceinline__ float gelu_fast(float x) {
    float t = x * fmaf(x * x, 0.044715f, 1.0f);
    float e = __builtin_amdgcn_exp2f(-2.3022078f * t);
    return x * __builtin_amdgcn_rcpf(1.0f + e);
}
__device__ __forceinline__ bf16x8 ldsfrag(const u16* base, int byte) {
    return *(const bf16x8*)((const char*)base + byte);
}
__device__ __forceinline__ bf16x8 ldg8(const u16* __restrict__ p) {
    return *(const bf16x8*)p;
}
// wg in [0,256): group of 4 windows; tok in [0,64).
template <int BRANCH>
__device__ __forceinline__ int src_index(int wg, int tok) {
    int win = (wg << 2) + (tok >> 4), p = tok & 15;
    int r = ((win >> 5) << 2) | (p >> 2);
    int c = ((win & 31) << 2) | (p & 3);
    if (BRANCH == 1) return (r << 7) | c;
    int r2 = (r + 2) & 127, c2 = (c + 2) & 127;
    return ((((r2 >> 2) << 5) | (c2 >> 2)) << 4) | ((r2 & 3) << 2) | (c2 & 3);
}

// ---------------------------------------------------------------------------
// Weight fp32 -> bf16 prep.
// ---------------------------------------------------------------------------
__global__ __launch_bounds__(256)
void cvt_weights(const float* __restrict__ qkv1, const float* __restrict__ o1,
                 const float* __restrict__ w11,  const float* __restrict__ w12,
                 const float* __restrict__ qkv2, const float* __restrict__ o2,
                 const float* __restrict__ w21,  const float* __restrict__ w22,
                 u16* __restrict__ dst)
{
    int e = (blockIdx.x * 256 + threadIdx.x) * 8;
    const float* src; int off;
    if      (e < 49152)  { src = qkv1; off = 0; }
    else if (e < 65536)  { src = o1;   off = 49152; }
    else if (e < 131072) { src = w11;  off = 65536; }
    else if (e < 196608) { src = w12;  off = 131072; }
    else if (e < 245760) { src = qkv2; off = 196608; }
    else if (e < 262144) { src = o2;   off = 245760; }
    else if (e < 327680) { src = w21;  off = 262144; }
    else                 { src = w22;  off = 327680; }
    float4 a = *(const float4*)(src + (e - off));
    float4 b = *(const float4*)(src + (e - off) + 4);
    uint4 o;
    o.x = pack2(a.x, a.y); o.y = pack2(a.z, a.w);
    o.z = pack2(b.x, b.y); o.w = pack2(b.z, b.w);
    *(uint4*)(dst + e) = o;
}

// ---------------------------------------------------------------------------
// Fused half-block: LN_A + windowed MHSA + residual(LDS) + LN_B + MLP.
// LDS (81920 B = exactly 2 blocks/CU):
//   xs[64][256B]@0 | qls[64][256B]@16K | kls[64][256B]@32K | vt[128][256B]@48K
// Overlays: resf fp32 [64][512B] = qls+kls; P[64][128B] = qls;
//           h1a = vt@48K, h1b = vt@64K (16K each, double-buffered MLP hidden).
// ---------------------------------------------------------------------------
template <int BRANCH>
__global__ __launch_bounds__(512, 4)
void swin_fused(const float* __restrict__ xin,   // LN_A source
                const float* __restrict__ resin, // residual source
                float* __restrict__ resout,      // output
                const float* __restrict__ lnA_g, const float* __restrict__ lnA_b,
                const float* __restrict__ lnB_g, const float* __restrict__ lnB_b,
                const u16* __restrict__ qkvw, const float* __restrict__ qkvb,
                const u16* __restrict__ ow,   const float* __restrict__ ob,
                const u16* __restrict__ w1,   const float* __restrict__ b1,
                const u16* __restrict__ w2,   const float* __restrict__ b2)
{
    __shared__ __align__(16) char smem[81920];
    u16*   xs   = (u16*)smem;
    u16*   qls  = (u16*)(smem + 16384);
    u16*   kls  = (u16*)(smem + 32768);
    u16*   vt   = (u16*)(smem + 49152);
    float* resf = (float*)(smem + 16384);
    u16*   h1a  = (u16*)(smem + 49152);
    u16*   h1b  = (u16*)(smem + 65536);

    const int t  = threadIdx.x;
    const int wv = t >> 6, ln = t & 63, l15 = ln & 15, q4 = ln >> 4;
    const int bb = blockIdx.x >> 8, wg = blockIdx.x & 255;
    const int xa = (l15 & 7) << 4;
    const size_t gbase = (size_t)bb * 16384;

    // ---------- phase 0: gather + LN_A -> xs (bf16); zero vt pad ----------
    {
        int token = t >> 3, part = t & 7;               // 8 thr/token, 16 dims each
        int nsrc = src_index<BRANCH>(wg, token);
        const float* src = xin + (gbase + nsrc) * 128;
        float v[16];
#pragma unroll
        for (int j = 0; j < 4; ++j)
            *(float4*)&v[j * 4] = *(const float4*)(src + part * 4 + 32 * j);
        float s = 0.f, s2 = 0.f;
#pragma unroll
        for (int i = 0; i < 16; ++i) { s += v[i]; s2 += v[i] * v[i]; }
        s  += __shfl_xor(s, 1, 8);  s  += __shfl_xor(s, 2, 8);  s  += __shfl_xor(s, 4, 8);
        s2 += __shfl_xor(s2, 1, 8); s2 += __shfl_xor(s2, 2, 8); s2 += __shfl_xor(s2, 4, 8);
        float mu = s * (1.f / 128.f);
        float rstd = rsqrtf(s2 * (1.f / 128.f) - mu * mu + 1e-5f);
        int xk = (token & 7) << 4;
#pragma unroll
        for (int j = 0; j < 4; ++j) {
            int d0 = part * 4 + 32 * j;
            float a0 = (v[j * 4 + 0] - mu) * rstd * lnA_g[d0]     + lnA_b[d0];
            float a1 = (v[j * 4 + 1] - mu) * rstd * lnA_g[d0 + 1] + lnA_b[d0 + 1];
            float a2 = (v[j * 4 + 2] - mu) * rstd * lnA_g[d0 + 2] + lnA_b[d0 + 2];
            float a3 = (v[j * 4 + 3] - mu) * rstd * lnA_g[d0 + 3] + lnA_b[d0 + 3];
            int byte = token * 256 + ((part * 8 + j * 64) ^ xk);
            *(uint2*)((char*)xs + byte) = make_uint2(pack2(a0, a1), pack2(a2, a3));
        }
        // zero vt pad: all 128 rows, bytes [128,256)
        int row = t >> 2, base = row * 256 + 128 + (t & 3) * 32;
        uint4 z = {0, 0, 0, 0};
        *(uint4*)((char*)vt + base)      = z;
        *(uint4*)((char*)vt + base + 16) = z;
    }
    __syncthreads();

    // ---------- phase 1: QKV GEMM (M=64, N=384, K=128), inline weight loads ----------
#pragma unroll 1
    for (int i = 0; i < 3; ++i) {
        int n0 = (wv * 3 + i) * 16;
        int part = n0 >> 7, c0 = n0 & 127;
        float bias = qkvb[n0 + l15];
        f32x4 acc[4];
#pragma unroll
        for (int mf = 0; mf < 4; ++mf) acc[mf] = (f32x4){bias, bias, bias, bias};
#pragma unroll
        for (int kf = 0; kf < 4; ++kf) {
            bf16x8 bfr = ldg8(qkvw + (size_t)(n0 + l15) * 128 + kf * 32 + q4 * 8);
#pragma unroll
            for (int mf = 0; mf < 4; ++mf) {
                bf16x8 afr = ldsfrag(xs, (mf * 16 + l15) * 256 + ((kf * 64 + q4 * 16) ^ xa));
                acc[mf] = MFMA(afr, bfr, acc[mf]);
            }
        }
        if (part < 2) {                       // q (scaled) / k, token-major
            u16* dst = part ? kls : qls;
            float sc = part ? 1.f : 0.125f;
#pragma unroll
            for (int mf = 0; mf < 4; ++mf)
#pragma unroll
                for (int r = 0; r < 4; ++r) {
                    int tok = mf * 16 + q4 * 4 + r;
                    int byte = tok * 256 + ((2 * (c0 + l15)) ^ ((tok & 7) << 4));
                    dst[byte >> 1] = f2bf(acc[mf][r] * sc);
                }
        } else {                              // v -> vt[dh][tok], 256B stride
            int dh = c0 + l15, xr = (dh & 7) << 4;
#pragma unroll
            for (int mf = 0; mf < 4; ++mf) {
                int tok0 = mf * 16 + q4 * 4;
                u32 lo = pack2(acc[mf][0], acc[mf][1]);
                u32 hi = pack2(acc[mf][2], acc[mf][3]);
                int byte = dh * 256 + ((2 * tok0) ^ xr);
                *(uint2*)((char*)vt + byte) = make_uint2(lo, hi);
            }
        }
    }
    __syncthreads();

    // ---------- phase 2: scores. 1 (window,head) pair per wave ----------
    f32x4 S;
    {
        int win = wv >> 1, h = wv & 1;
        f32x4 z = {0.f, 0.f, 0.f, 0.f};
        int tok = win * 16 + l15, xk = (tok & 7) << 4;
#pragma unroll
        for (int kf = 0; kf < 2; ++kf) {
            int byte = tok * 256 + ((h * 128 + kf * 64 + q4 * 16) ^ xk);
            bf16x8 aq = ldsfrag(qls, byte);
            bf16x8 bk = ldsfrag(kls, byte);
            z = MFMA(aq, bk, z);
        }
        S = z;
    }
    __syncthreads();   // q reads done before P overlays qls

    // ---------- softmax in-register; P (bf16, K padded to 32) -> qls ----------
    {
        int win = wv >> 1, h = wv & 1;
#pragma unroll
        for (int r = 0; r < 4; ++r) {
            float v = S[r];
            float m = v;
            m = fmaxf(m, __shfl_xor(m, 1, 16)); m = fmaxf(m, __shfl_xor(m, 2, 16));
            m = fmaxf(m, __shfl_xor(m, 4, 16)); m = fmaxf(m, __shfl_xor(m, 8, 16));
            float e = __builtin_amdgcn_exp2f((v - m) * 1.44269504f);
            float sm = e;
            sm += __shfl_xor(sm, 1, 16); sm += __shfl_xor(sm, 2, 16);
            sm += __shfl_xor(sm, 4, 16); sm += __shfl_xor(sm, 8, 16);
            float p = e * __builtin_amdgcn_rcpf(sm);
            int tok = win * 16 + q4 * 4 + r, xk = (tok & 7) << 4;
            qls[(tok * 128 + ((h * 64 + l15 * 2)      ^ xk)) >> 1] = f2bf(p);
            qls[(tok * 128 + ((h * 64 + 32 + l15 * 2) ^ xk)) >> 1] = 0;
        }
    }
    __syncthreads();

    // ---------- phase 3: PV -> xs (attn-out bf16) ----------
    {
        int win = wv >> 1, h = wv & 1;
        int atok = win * 16 + l15;
        bf16x8 ap = ldsfrag(qls, atok * 128 + ((h * 64 + q4 * 16) ^ ((atok & 7) << 4)));
#pragma unroll
        for (int nf = 0; nf < 4; ++nf) {
            int dh = h * 64 + nf * 16 + l15;
            bf16x8 bv = ldsfrag(vt, dh * 256 + ((win * 32 + q4 * 16) ^ ((dh & 7) << 4)));
            f32x4 z = {0.f, 0.f, 0.f, 0.f};
            f32x4 o = MFMA(ap, bv, z);
#pragma unroll
            for (int r = 0; r < 4; ++r) {
                int tok = win * 16 + q4 * 4 + r;
                xs[(tok * 256 + ((2 * dh) ^ ((tok & 7) << 4))) >> 1] = f2bf(o[r]);
            }
        }
    }
    __syncthreads();

    // ---------- phase 4: output projection + residual -> resf (LDS fp32) ----------
    {
        int n0 = wv * 16;
        float bias = ob[n0 + l15];
        f32x4 acc[4];
#pragma unroll
        for (int mf = 0; mf < 4; ++mf) acc[mf] = (f32x4){bias, bias, bias, bias};
#pragma unroll
        for (int kf = 0; kf < 4; ++kf) {
            bf16x8 bfr = ldg8(ow + (size_t)(n0 + l15) * 128 + kf * 32 + q4 * 8);
#pragma unroll
            for (int mf = 0; mf < 4; ++mf) {
                bf16x8 afr = ldsfrag(xs, (mf * 16 + l15) * 256 + ((kf * 64 + q4 * 16) ^ xa));
                acc[mf] = MFMA(afr, bfr, acc[mf]);
            }
        }
#pragma unroll
        for (int mf = 0; mf < 4; ++mf)
#pragma unroll
            for (int r = 0; r < 4; ++r) {
                int tok = mf * 16 + q4 * 4 + r;
                int nd = (BRANCH == 1) ? (wg * 64 + tok) : src_index<2>(wg, tok);
                float rv = resin[(gbase + nd) * 128 + n0 + l15];
                if (BRANCH == 1) rv = truncf(rv);
                int byte = tok * 512 + ((4 * (n0 + l15)) ^ ((tok & 7) << 4));
                *(float*)((char*)resf + byte) = rv + acc[mf][r];
            }
    }
    __syncthreads();

    // ---------- phase 5: LN_B over resf -> xs (bf16) ----------
    // resf stores dim d at physical byte (4d)^xk (xk 16-aligned), so reading
    // physical chunk ((part*16+j*128)^xk) yields LOGICAL dims part*4+32j.
    {
        int token = t >> 3, part = t & 7;
        int xk = (token & 7) << 4;
        float v[16];
#pragma unroll
        for (int j = 0; j < 4; ++j)
            *(float4*)&v[j * 4] =
                *(const float4*)((char*)resf + token * 512 + ((part * 16 + j * 128) ^ xk));
        float s = 0.f, s2 = 0.f;
#pragma unroll
        for (int i = 0; i < 16; ++i) { s += v[i]; s2 += v[i] * v[i]; }
        s  += __shfl_xor(s, 1, 8);  s  += __shfl_xor(s, 2, 8);  s  += __shfl_xor(s, 4, 8);
        s2 += __shfl_xor(s2, 1, 8); s2 += __shfl_xor(s2, 2, 8); s2 += __shfl_xor(s2, 4, 8);
        float mu = s * (1.f / 128.f);
        float rstd = rsqrtf(s2 * (1.f / 128.f) - mu * mu + 1e-5f);
#pragma unroll
        for (int j = 0; j < 4; ++j) {
            int d0 = part * 4 + 32 * j;
            float a0 = (v[j * 4 + 0] - mu) * rstd * lnB_g[d0]     + lnB_b[d0];
            float a1 = (v[j * 4 + 1] - mu) * rstd * lnB_g[d0 + 1] + lnB_b[d0 + 1];
            float a2 = (v[j * 4 + 2] - mu) * rstd * lnB_g[d0 + 2] + lnB_b[d0 + 2];
            float a3 = (v[j * 4 + 3] - mu) * rstd * lnB_g[d0 + 3] + lnB_b[d0 + 3];
            int byte = token * 256 + ((part * 8 + j * 64) ^ xk);
            *(uint2*)((char*)xs + byte) = make_uint2(pack2(a0, a1), pack2(a2, a3));
        }
    }
    __syncthreads();

    // ---------- phase 6: MLP, 4 chunks x 128 h1-cols, double-buffered h1,
    //            inline weight loads (compiler-budgeted hoisting).
    const int nm = wv * 16;
    f32x4 acc2[4];
    {
        float bias = b2[nm + l15];
#pragma unroll
        for (int mf = 0; mf < 4; ++mf) acc2[mf] = (f32x4){bias, bias, bias, bias};
    }
    // chunk 0: GEMM1 only
    {
        float bias = b1[nm + l15];
        f32x4 acc1[4];
#pragma unroll
        for (int mf = 0; mf < 4; ++mf) acc1[mf] = (f32x4){bias, bias, bias, bias};
#pragma unroll
        for (int kf = 0; kf < 4; ++kf) {
            bf16x8 bfr = ldg8(w1 + (size_t)(nm + l15) * 128 + kf * 32 + q4 * 8);
#pragma unroll
            for (int mf = 0; mf < 4; ++mf) {
                bf16x8 afr = ldsfrag(xs, (mf * 16 + l15) * 256 + ((kf * 64 + q4 * 16) ^ xa));
                acc1[mf] = MFMA(afr, bfr, acc1[mf]);
            }
        }
#pragma unroll
        for (int mf = 0; mf < 4; ++mf)
#pragma unroll
            for (int r = 0; r < 4; ++r) {
                int tok = mf * 16 + q4 * 4 + r;
                h1a[(tok * 256 + ((2 * (nm + l15)) ^ ((tok & 7) << 4))) >> 1] =
                    f2bf(gelu_fast(acc1[mf][r]));
            }
    }
    __syncthreads();
#pragma unroll 1
    for (int c = 1; c < 4; ++c) {
        u16* hcur  = (c & 1) ? h1b : h1a;   // G1(c) store target
        u16* hprev = (c & 1) ? h1a : h1b;   // G2(c-1) source
        // G2(c-1)
#pragma unroll
        for (int kf = 0; kf < 4; ++kf) {
            bf16x8 bfr = ldg8(w2 + (size_t)(nm + l15) * 512 + (c - 1) * 128 + kf * 32 + q4 * 8);
#pragma unroll
            for (int mf = 0; mf < 4; ++mf) {
                bf16x8 afr = ldsfrag(hprev, (mf * 16 + l15) * 256 + ((kf * 64 + q4 * 16) ^ xa));
                acc2[mf] = MFMA(afr, bfr, acc2[mf]);
            }
        }
        // G1(c)
        float bias = b1[c * 128 + nm + l15];
        f32x4 acc1[4];
#pragma unroll
        for (int mf = 0; mf < 4; ++mf) acc1[mf] = (f32x4){bias, bias, bias, bias};
#pragma unroll
        for (int kf = 0; kf < 4; ++kf) {
            bf16x8 bfr = ldg8(w1 + (size_t)(c * 128 + nm + l15) * 128 + kf * 32 + q4 * 8);
#pragma unroll
            for (int mf = 0; mf < 4; ++mf) {
                bf16x8 afr = ldsfrag(xs, (mf * 16 + l15) * 256 + ((kf * 64 + q4 * 16) ^ xa));
                acc1[mf] = MFMA(afr, bfr, acc1[mf]);
            }
        }
#pragma unroll
        for (int mf = 0; mf < 4; ++mf)
#pragma unroll
            for (int r = 0; r < 4; ++r) {
                int tok = mf * 16 + q4 * 4 + r;
                hcur[(tok * 256 + ((2 * (nm + l15)) ^ ((tok & 7) << 4))) >> 1] =
                    f2bf(gelu_fast(acc1[mf][r]));
            }
        __syncthreads();
    }
    // tail: G2(3) from h1b
    {
#pragma unroll
        for (int kf = 0; kf < 4; ++kf) {
            bf16x8 bfr = ldg8(w2 + (size_t)(nm + l15) * 512 + 384 + kf * 32 + q4 * 8);
#pragma unroll
            for (int mf = 0; mf < 4; ++mf) {
                bf16x8 afr = ldsfrag(h1b, (mf * 16 + l15) * 256 + ((kf * 64 + q4 * 16) ^ xa));
                acc2[mf] = MFMA(afr, bfr, acc2[mf]);
            }
        }
    }

    // ---------- phase 7: out = gelu(acc2) + resf -> global ----------
#pragma unroll
    for (int mf = 0; mf < 4; ++mf)
#pragma unroll
        for (int r = 0; r < 4; ++r) {
            int tok = mf * 16 + q4 * 4 + r;
            int nd = (BRANCH == 1) ? (wg * 64 + tok) : src_index<2>(wg, tok);
            float res = *(const float*)((char*)resf +
                            tok * 512 + ((4 * (nm + l15)) ^ ((tok & 7) << 4)));
            resout[(gbase + nd) * 128 + nm + l15] = gelu_fast(acc2[mf][r]) + res;
        }
}

extern "C" void kernel_launch(void* const* d_in, const int* in_sizes, int n_in,
                              void* d_out, int out_size, void* d_ws, size_t ws_size,
                              hipStream_t stream) {
    (void)in_sizes; (void)n_in; (void)out_size; (void)ws_size;
    const float* x      = (const float*)d_in[0];
    const float* ln1_g  = (const float*)d_in[1];
    const float* ln1_b  = (const float*)d_in[2];
    const float* ln2_g  = (const float*)d_in[3];
    const float* ln2_b  = (const float*)d_in[4];
    const float* ln3_g  = (const float*)d_in[5];
    const float* ln3_b  = (const float*)d_in[6];
    const float* ln4_g  = (const float*)d_in[7];
    const float* ln4_b  = (const float*)d_in[8];
    const float* qkv1_w = (const float*)d_in[9];
    const float* qkv1_b = (const float*)d_in[10];
    const float* out1_w = (const float*)d_in[11];
    const float* out1_b = (const float*)d_in[12];
    const float* qkv2_w = (const float*)d_in[13];
    const float* qkv2_b = (const float*)d_in[14];
    const float* out2_w = (const float*)d_in[15];
    const float* out2_b = (const float*)d_in[16];
    const float* mlp1_w1 = (const float*)d_in[17];
    const float* mlp1_b1 = (const float*)d_in[18];
    const float* mlp1_w2 = (const float*)d_in[19];
    const float* mlp1_b2 = (const float*)d_in[20];
    const float* mlp2_w1 = (const float*)d_in[21];
    const float* mlp2_b1 = (const float*)d_in[22];
    const float* mlp2_w2 = (const float*)d_in[23];
    const float* mlp2_b2 = (const float*)d_in[24];

    // bf16 weights in d_ws (786 KiB total)
    u16* wb = (u16*)d_ws;
    u16* qkv1bf = wb + 0;
    u16* out1bf = wb + 49152;
    u16* m1w1bf = wb + 65536;
    u16* m1w2bf = wb + 131072;
    u16* qkv2bf = wb + 196608;
    u16* out2bf = wb + 245760;
    u16* m2w1bf = wb + 262144;
    u16* m2w2bf = wb + 327680;

    float* out = (float*)d_out;

    cvt_weights<<<dim3(192), dim3(256), 0, stream>>>(
        qkv1_w, out1_w, mlp1_w1, mlp1_w2, qkv2_w, out2_w, mlp2_w1, mlp2_w2, wb);

    // K1: W-MSA + MLP1 -> out1 (writes every element of d_out)
    swin_fused<1><<<dim3(2048), dim3(512), 0, stream>>>(
        x, x, out,
        ln1_g, ln1_b, ln2_g, ln2_b,
        qkv1bf, qkv1_b, out1bf, out1_b,
        m1w1bf, mlp1_b1, m1w2bf, mlp1_b2);

    // K2: SW-MSA + MLP2 -> out2, in place (block gather set == scatter set)
    swin_fused<2><<<dim3(2048), dim3(512), 0, stream>>>(
        out, out, out,
        ln3_g, ln3_b, ln4_g, ln4_b,
        qkv2bf, qkv2_b, out2bf, out2_b,
        m2w1bf, mlp2_b1, m2w2bf, mlp2_b2);
}

// Round 12
// 277.084 us; speedup vs baseline: 1.2871x; 1.1758x over previous
//
#include <hip/hip_runtime.h>
#include <hip/hip_bf16.h>
#include <string.h>

// B=8, N=16384 (H=W=128), D=128, WS=4 -> nW=1024, P=16 tok/window, NH=2, dh=64.
// Two fused kernels (K1: LN1+W-MSA+res1+LN2+MLP1; K2: LN3+SW-MSA+res2+LN4+MLP2).
// Block = 64 tokens (4 windows), 512 threads (8 waves), LDS 80K -> 2 blocks/CU.
// Reg discipline at the (512,4) 128-reg cap (R10/R11 WRITE_SIZE evidence):
//   - weight loads INLINE in MFMA loops (no hand-hoisted frag arrays)
//   - MLP G1 and G2 in SEPARATE barrier regions (don't co-schedule two weight
//     streams + two accumulators; the merged form spilled 114 MB/dispatch)

typedef unsigned short u16;
typedef unsigned int   u32;
typedef __attribute__((ext_vector_type(8))) short bf16x8;
typedef __attribute__((ext_vector_type(4))) float f32x4;

#define MFMA(a,b,c) __builtin_amdgcn_mfma_f32_16x16x32_bf16(a,b,c,0,0,0)

// compiler-generated v_cvt_bf16_f32 / v_cvt_pk_bf16_f32 (RNE).
__device__ __forceinline__ u16 f2bf(float x) {
    __hip_bfloat16 h = __float2bfloat16(x);
    u16 r; memcpy(&r, &h, 2); return r;
}
__device__ __forceinline__ u32 pack2(float lo, float hi) {
    __hip_bfloat162 h = __float22bfloat162_rn(make_float2(lo, hi));
    u32 r; memcpy(&r, &h, 4); return r;
}
// tanh-form GELU via hw exp2 + rcp. |err| vs exact erf-GELU < ~1e-3.
__device__ __forceinline__ float gelu_fast(float x) {
    float t = x * fmaf(x * x, 0.044715f, 1.0f);
    float e = __builtin_amdgcn_exp2f(-2.3022078f * t);
    return x * __builtin_amdgcn_rcpf(1.0f + e);
}
__device__ __forceinline__ bf16x8 ldsfrag(const u16* base, int byte) {
    return *(const bf16x8*)((const char*)base + byte);
}
__device__ __forceinline__ bf16x8 ldg8(const u16* __restrict__ p) {
    return *(const bf16x8*)p;
}
// wg in [0,256): group of 4 windows; tok in [0,64).
template <int BRANCH>
__device__ __forceinline__ int src_index(int wg, int tok) {
    int win = (wg << 2) + (tok >> 4), p = tok & 15;
    int r = ((win >> 5) << 2) | (p >> 2);
    int c = ((win & 31) << 2) | (p & 3);
    if (BRANCH == 1) return (r << 7) | c;
    int r2 = (r + 2) & 127, c2 = (c + 2) & 127;
    return ((((r2 >> 2) << 5) | (c2 >> 2)) << 4) | ((r2 & 3) << 2) | (c2 & 3);
}

// ---------------------------------------------------------------------------
// Weight fp32 -> bf16 prep.
// ---------------------------------------------------------------------------
__global__ __launch_bounds__(256)
void cvt_weights(const float* __restrict__ qkv1, const float* __restrict__ o1,
                 const float* __restrict__ w11,  const float* __restrict__ w12,
                 const float* __restrict__ qkv2, const float* __restrict__ o2,
                 const float* __restrict__ w21,  const float* __restrict__ w22,
                 u16* __restrict__ dst)
{
    int e = (blockIdx.x * 256 + threadIdx.x) * 8;
    const float* src; int off;
    if      (e < 49152)  { src = qkv1; off = 0; }
    else if (e < 65536)  { src = o1;   off = 49152; }
    else if (e < 131072) { src = w11;  off = 65536; }
    else if (e < 196608) { src = w12;  off = 131072; }
    else if (e < 245760) { src = qkv2; off = 196608; }
    else if (e < 262144) { src = o2;   off = 245760; }
    else if (e < 327680) { src = w21;  off = 262144; }
    else                 { src = w22;  off = 327680; }
    float4 a = *(const float4*)(src + (e - off));
    float4 b = *(const float4*)(src + (e - off) + 4);
    uint4 o;
    o.x = pack2(a.x, a.y); o.y = pack2(a.z, a.w);
    o.z = pack2(b.x, b.y); o.w = pack2(b.z, b.w);
    *(uint4*)(dst + e) = o;
}

// ---------------------------------------------------------------------------
// Fused half-block: LN_A + windowed MHSA + residual(LDS) + LN_B + MLP.
// LDS (81920 B = exactly 2 blocks/CU):
//   xs[64][256B]@0 | qls[64][256B]@16K | kls[64][256B]@32K | vt[128][256B]@48K
// Overlays: resf fp32 [64][512B] = qls+kls; P[64][128B] = qls;
//           h1 [64][256B] = vt@48K (single-buffered MLP hidden chunk).
// ---------------------------------------------------------------------------
template <int BRANCH>
__global__ __launch_bounds__(512, 4)
void swin_fused(const float* __restrict__ xin,   // LN_A source
                const float* __restrict__ resin, // residual source
                float* __restrict__ resout,      // output
                const float* __restrict__ lnA_g, const float* __restrict__ lnA_b,
                const float* __restrict__ lnB_g, const float* __restrict__ lnB_b,
                const u16* __restrict__ qkvw, const float* __restrict__ qkvb,
                const u16* __restrict__ ow,   const float* __restrict__ ob,
                const u16* __restrict__ w1,   const float* __restrict__ b1,
                const u16* __restrict__ w2,   const float* __restrict__ b2)
{
    __shared__ __align__(16) char smem[81920];
    u16*   xs   = (u16*)smem;
    u16*   qls  = (u16*)(smem + 16384);
    u16*   kls  = (u16*)(smem + 32768);
    u16*   vt   = (u16*)(smem + 49152);
    float* resf = (float*)(smem + 16384);
    u16*   h1   = (u16*)(smem + 49152);

    const int t  = threadIdx.x;
    const int wv = t >> 6, ln = t & 63, l15 = ln & 15, q4 = ln >> 4;
    const int bb = blockIdx.x >> 8, wg = blockIdx.x & 255;
    const int xa = (l15 & 7) << 4;
    const size_t gbase = (size_t)bb * 16384;

    // ---------- phase 0: gather + LN_A -> xs (bf16); zero vt pad ----------
    {
        int token = t >> 3, part = t & 7;               // 8 thr/token, 16 dims each
        int nsrc = src_index<BRANCH>(wg, token);
        const float* src = xin + (gbase + nsrc) * 128;
        float v[16];
#pragma unroll
        for (int j = 0; j < 4; ++j)
            *(float4*)&v[j * 4] = *(const float4*)(src + part * 4 + 32 * j);
        float s = 0.f, s2 = 0.f;
#pragma unroll
        for (int i = 0; i < 16; ++i) { s += v[i]; s2 += v[i] * v[i]; }
        s  += __shfl_xor(s, 1, 8);  s  += __shfl_xor(s, 2, 8);  s  += __shfl_xor(s, 4, 8);
        s2 += __shfl_xor(s2, 1, 8); s2 += __shfl_xor(s2, 2, 8); s2 += __shfl_xor(s2, 4, 8);
        float mu = s * (1.f / 128.f);
        float rstd = rsqrtf(s2 * (1.f / 128.f) - mu * mu + 1e-5f);
        int xk = (token & 7) << 4;
#pragma unroll
        for (int j = 0; j < 4; ++j) {
            int d0 = part * 4 + 32 * j;
            float a0 = (v[j * 4 + 0] - mu) * rstd * lnA_g[d0]     + lnA_b[d0];
            float a1 = (v[j * 4 + 1] - mu) * rstd * lnA_g[d0 + 1] + lnA_b[d0 + 1];
            float a2 = (v[j * 4 + 2] - mu) * rstd * lnA_g[d0 + 2] + lnA_b[d0 + 2];
            float a3 = (v[j * 4 + 3] - mu) * rstd * lnA_g[d0 + 3] + lnA_b[d0 + 3];
            int byte = token * 256 + ((part * 8 + j * 64) ^ xk);
            *(uint2*)((char*)xs + byte) = make_uint2(pack2(a0, a1), pack2(a2, a3));
        }
        // zero vt pad: all 128 rows, bytes [128,256)
        int row = t >> 2, base = row * 256 + 128 + (t & 3) * 32;
        uint4 z = {0, 0, 0, 0};
        *(uint4*)((char*)vt + base)      = z;
        *(uint4*)((char*)vt + base + 16) = z;
    }
    __syncthreads();

    // ---------- phase 1: QKV GEMM (M=64, N=384, K=128), inline weight loads ----------
#pragma unroll 1
    for (int i = 0; i < 3; ++i) {
        int n0 = (wv * 3 + i) * 16;
        int part = n0 >> 7, c0 = n0 & 127;
        float bias = qkvb[n0 + l15];
        f32x4 acc[4];
#pragma unroll
        for (int mf = 0; mf < 4; ++mf) acc[mf] = (f32x4){bias, bias, bias, bias};
#pragma unroll
        for (int kf = 0; kf < 4; ++kf) {
            bf16x8 bfr = ldg8(qkvw + (size_t)(n0 + l15) * 128 + kf * 32 + q4 * 8);
#pragma unroll
            for (int mf = 0; mf < 4; ++mf) {
                bf16x8 afr = ldsfrag(xs, (mf * 16 + l15) * 256 + ((kf * 64 + q4 * 16) ^ xa));
                acc[mf] = MFMA(afr, bfr, acc[mf]);
            }
        }
        if (part < 2) {                       // q (scaled) / k, token-major
            u16* dst = part ? kls : qls;
            float sc = part ? 1.f : 0.125f;
#pragma unroll
            for (int mf = 0; mf < 4; ++mf)
#pragma unroll
                for (int r = 0; r < 4; ++r) {
                    int tok = mf * 16 + q4 * 4 + r;
                    int byte = tok * 256 + ((2 * (c0 + l15)) ^ ((tok & 7) << 4));
                    dst[byte >> 1] = f2bf(acc[mf][r] * sc);
                }
        } else {                              // v -> vt[dh][tok], 256B stride
            int dh = c0 + l15, xr = (dh & 7) << 4;
#pragma unroll
            for (int mf = 0; mf < 4; ++mf) {
                int tok0 = mf * 16 + q4 * 4;
                u32 lo = pack2(acc[mf][0], acc[mf][1]);
                u32 hi = pack2(acc[mf][2], acc[mf][3]);
                int byte = dh * 256 + ((2 * tok0) ^ xr);
                *(uint2*)((char*)vt + byte) = make_uint2(lo, hi);
            }
        }
    }
    __syncthreads();

    // ---------- phase 2: scores. 1 (window,head) pair per wave ----------
    f32x4 S;
    {
        int win = wv >> 1, h = wv & 1;
        f32x4 z = {0.f, 0.f, 0.f, 0.f};
        int tok = win * 16 + l15, xk = (tok & 7) << 4;
#pragma unroll
        for (int kf = 0; kf < 2; ++kf) {
            int byte = tok * 256 + ((h * 128 + kf * 64 + q4 * 16) ^ xk);
            bf16x8 aq = ldsfrag(qls, byte);
            bf16x8 bk = ldsfrag(kls, byte);
            z = MFMA(aq, bk, z);
        }
        S = z;
    }
    __syncthreads();   // q reads done before P overlays qls

    // ---------- softmax in-register; P (bf16, K padded to 32) -> qls ----------
    {
        int win = wv >> 1, h = wv & 1;
#pragma unroll
        for (int r = 0; r < 4; ++r) {
            float v = S[r];
            float m = v;
            m = fmaxf(m, __shfl_xor(m, 1, 16)); m = fmaxf(m, __shfl_xor(m, 2, 16));
            m = fmaxf(m, __shfl_xor(m, 4, 16)); m = fmaxf(m, __shfl_xor(m, 8, 16));
            float e = __builtin_amdgcn_exp2f((v - m) * 1.44269504f);
            float sm = e;
            sm += __shfl_xor(sm, 1, 16); sm += __shfl_xor(sm, 2, 16);
            sm += __shfl_xor(sm, 4, 16); sm += __shfl_xor(sm, 8, 16);
            float p = e * __builtin_amdgcn_rcpf(sm);
            int tok = win * 16 + q4 * 4 + r, xk = (tok & 7) << 4;
            qls[(tok * 128 + ((h * 64 + l15 * 2)      ^ xk)) >> 1] = f2bf(p);
            qls[(tok * 128 + ((h * 64 + 32 + l15 * 2) ^ xk)) >> 1] = 0;
        }
    }
    __syncthreads();

    // ---------- phase 3: PV -> xs (attn-out bf16) ----------
    {
        int win = wv >> 1, h = wv & 1;
        int atok = win * 16 + l15;
        bf16x8 ap = ldsfrag(qls, atok * 128 + ((h * 64 + q4 * 16) ^ ((atok & 7) << 4)));
#pragma unroll
        for (int nf = 0; nf < 4; ++nf) {
            int dh = h * 64 + nf * 16 + l15;
            bf16x8 bv = ldsfrag(vt, dh * 256 + ((win * 32 + q4 * 16) ^ ((dh & 7) << 4)));
            f32x4 z = {0.f, 0.f, 0.f, 0.f};
            f32x4 o = MFMA(ap, bv, z);
#pragma unroll
            for (int r = 0; r < 4; ++r) {
                int tok = win * 16 + q4 * 4 + r;
                xs[(tok * 256 + ((2 * dh) ^ ((tok & 7) << 4))) >> 1] = f2bf(o[r]);
            }
        }
    }
    __syncthreads();

    // ---------- phase 4: output projection + residual -> resf (LDS fp32) ----------
    {
        int n0 = wv * 16;
        float bias = ob[n0 + l15];
        f32x4 acc[4];
#pragma unroll
        for (int mf = 0; mf < 4; ++mf) acc[mf] = (f32x4){bias, bias, bias, bias};
#pragma unroll
        for (int kf = 0; kf < 4; ++kf) {
            bf16x8 bfr = ldg8(ow + (size_t)(n0 + l15) * 128 + kf * 32 + q4 * 8);
#pragma unroll
            for (int mf = 0; mf < 4; ++mf) {
                bf16x8 afr = ldsfrag(xs, (mf * 16 + l15) * 256 + ((kf * 64 + q4 * 16) ^ xa));
                acc[mf] = MFMA(afr, bfr, acc[mf]);
            }
        }
#pragma unroll
        for (int mf = 0; mf < 4; ++mf)
#pragma unroll
            for (int r = 0; r < 4; ++r) {
                int tok = mf * 16 + q4 * 4 + r;
                int nd = (BRANCH == 1) ? (wg * 64 + tok) : src_index<2>(wg, tok);
                float rv = resin[(gbase + nd) * 128 + n0 + l15];
                if (BRANCH == 1) rv = truncf(rv);
                int byte = tok * 512 + ((4 * (n0 + l15)) ^ ((tok & 7) << 4));
                *(float*)((char*)resf + byte) = rv + acc[mf][r];
            }
    }
    __syncthreads();

    // ---------- phase 5: LN_B over resf -> xs (bf16) ----------
    // resf stores dim d at physical byte (4d)^xk (xk 16-aligned), so reading
    // physical chunk ((part*16+j*128)^xk) yields LOGICAL dims part*4+32j.
    {
        int token = t >> 3, part = t & 7;
        int xk = (token & 7) << 4;
        float v[16];
#pragma unroll
        for (int j = 0; j < 4; ++j)
            *(float4*)&v[j * 4] =
                *(const float4*)((char*)resf + token * 512 + ((part * 16 + j * 128) ^ xk));
        float s = 0.f, s2 = 0.f;
#pragma unroll
        for (int i = 0; i < 16; ++i) { s += v[i]; s2 += v[i] * v[i]; }
        s  += __shfl_xor(s, 1, 8);  s  += __shfl_xor(s, 2, 8);  s  += __shfl_xor(s, 4, 8);
        s2 += __shfl_xor(s2, 1, 8); s2 += __shfl_xor(s2, 2, 8); s2 += __shfl_xor(s2, 4, 8);
        float mu = s * (1.f / 128.f);
        float rstd = rsqrtf(s2 * (1.f / 128.f) - mu * mu + 1e-5f);
#pragma unroll
        for (int j = 0; j < 4; ++j) {
            int d0 = part * 4 + 32 * j;
            float a0 = (v[j * 4 + 0] - mu) * rstd * lnB_g[d0]     + lnB_b[d0];
            float a1 = (v[j * 4 + 1] - mu) * rstd * lnB_g[d0 + 1] + lnB_b[d0 + 1];
            float a2 = (v[j * 4 + 2] - mu) * rstd * lnB_g[d0 + 2] + lnB_b[d0 + 2];
            float a3 = (v[j * 4 + 3] - mu) * rstd * lnB_g[d0 + 3] + lnB_b[d0 + 3];
            int byte = token * 256 + ((part * 8 + j * 64) ^ xk);
            *(uint2*)((char*)xs + byte) = make_uint2(pack2(a0, a1), pack2(a2, a3));
        }
    }
    __syncthreads();

    // ---------- phase 6: MLP, 4 chunks x 128 h1-cols, single h1 buffer,
    //            G1 and G2 in SEPARATE barrier regions (reg-pressure discipline).
    const int nm = wv * 16;
    f32x4 acc2[4];
    {
        float bias = b2[nm + l15];
#pragma unroll
        for (int mf = 0; mf < 4; ++mf) acc2[mf] = (f32x4){bias, bias, bias, bias};
    }
#pragma unroll 1
    for (int c = 0; c < 4; ++c) {
        // G1(c): acc1 = LN_B(res) @ W1[c*128+nm..]^T + b1
        float bias = b1[c * 128 + nm + l15];
        f32x4 acc1[4];
#pragma unroll
        for (int mf = 0; mf < 4; ++mf) acc1[mf] = (f32x4){bias, bias, bias, bias};
#pragma unroll
        for (int kf = 0; kf < 4; ++kf) {
            bf16x8 bfr = ldg8(w1 + (size_t)(c * 128 + nm + l15) * 128 + kf * 32 + q4 * 8);
#pragma unroll
            for (int mf = 0; mf < 4; ++mf) {
                bf16x8 afr = ldsfrag(xs, (mf * 16 + l15) * 256 + ((kf * 64 + q4 * 16) ^ xa));
                acc1[mf] = MFMA(afr, bfr, acc1[mf]);
            }
        }
        __syncthreads();   // prior G2 reads of h1 complete
#pragma unroll
        for (int mf = 0; mf < 4; ++mf)
#pragma unroll
            for (int r = 0; r < 4; ++r) {
                int tok = mf * 16 + q4 * 4 + r;
                h1[(tok * 256 + ((2 * (nm + l15)) ^ ((tok & 7) << 4))) >> 1] =
                    f2bf(gelu_fast(acc1[mf][r]));
            }
        __syncthreads();   // h1 chunk ready
        // G2(c): acc2 += h1 @ W2[nm.., c*128..]^T
#pragma unroll
        for (int kf = 0; kf < 4; ++kf) {
            bf16x8 bfr = ldg8(w2 + (size_t)(nm + l15) * 512 + c * 128 + kf * 32 + q4 * 8);
#pragma unroll
            for (int mf = 0; mf < 4; ++mf) {
                bf16x8 afr = ldsfrag(h1, (mf * 16 + l15) * 256 + ((kf * 64 + q4 * 16) ^ xa));
                acc2[mf] = MFMA(afr, bfr, acc2[mf]);
            }
        }
    }

    // ---------- phase 7: out = gelu(acc2) + resf -> global ----------
#pragma unroll
    for (int mf = 0; mf < 4; ++mf)
#pragma unroll
        for (int r = 0; r < 4; ++r) {
            int tok = mf * 16 + q4 * 4 + r;
            int nd = (BRANCH == 1) ? (wg * 64 + tok) : src_index<2>(wg, tok);
            float res = *(const float*)((char*)resf +
                            tok * 512 + ((4 * (nm + l15)) ^ ((tok & 7) << 4)));
            resout[(gbase + nd) * 128 + nm + l15] = gelu_fast(acc2[mf][r]) + res;
        }
}

extern "C" void kernel_launch(void* const* d_in, const int* in_sizes, int n_in,
                              void* d_out, int out_size, void* d_ws, size_t ws_size,
                              hipStream_t stream) {
    (void)in_sizes; (void)n_in; (void)out_size; (void)ws_size;
    const float* x      = (const float*)d_in[0];
    const float* ln1_g  = (const float*)d_in[1];
    const float* ln1_b  = (const float*)d_in[2];
    const float* ln2_g  = (const float*)d_in[3];
    const float* ln2_b  = (const float*)d_in[4];
    const float* ln3_g  = (const float*)d_in[5];
    const float* ln3_b  = (const float*)d_in[6];
    const float* ln4_g  = (const float*)d_in[7];
    const float* ln4_b  = (const float*)d_in[8];
    const float* qkv1_w = (const float*)d_in[9];
    const float* qkv1_b = (const float*)d_in[10];
    const float* out1_w = (const float*)d_in[11];
    const float* out1_b = (const float*)d_in[12];
    const float* qkv2_w = (const float*)d_in[13];
    const float* qkv2_b = (const float*)d_in[14];
    const float* out2_w = (const float*)d_in[15];
    const float* out2_b = (const float*)d_in[16];
    const float* mlp1_w1 = (const float*)d_in[17];
    const float* mlp1_b1 = (const float*)d_in[18];
    const float* mlp1_w2 = (const float*)d_in[19];
    const float* mlp1_b2 = (const float*)d_in[20];
    const float* mlp2_w1 = (const float*)d_in[21];
    const float* mlp2_b1 = (const float*)d_in[22];
    const float* mlp2_w2 = (const float*)d_in[23];
    const float* mlp2_b2 = (const float*)d_in[24];

    // bf16 weights in d_ws (786 KiB total)
    u16* wb = (u16*)d_ws;
    u16* qkv1bf = wb + 0;
    u16* out1bf = wb + 49152;
    u16* m1w1bf = wb + 65536;
    u16* m1w2bf = wb + 131072;
    u16* qkv2bf = wb + 196608;
    u16* out2bf = wb + 245760;
    u16* m2w1bf = wb + 262144;
    u16* m2w2bf = wb + 327680;

    float* out = (float*)d_out;

    cvt_weights<<<dim3(192), dim3(256), 0, stream>>>(
        qkv1_w, out1_w, mlp1_w1, mlp1_w2, qkv2_w, out2_w, mlp2_w1, mlp2_w2, wb);

    // K1: W-MSA + MLP1 -> out1 (writes every element of d_out)
    swin_fused<1><<<dim3(2048), dim3(512), 0, stream>>>(
        x, x, out,
        ln1_g, ln1_b, ln2_g, ln2_b,
        qkv1bf, qkv1_b, out1bf, out1_b,
        m1w1bf, mlp1_b1, m1w2bf, mlp1_b2);

    // K2: SW-MSA + MLP2 -> out2, in place (block gather set == scatter set)
    swin_fused<2><<<dim3(2048), dim3(512), 0, stream>>>(
        out, out, out,
        ln3_g, ln3_b, ln4_g, ln4_b,
        qkv2bf, qkv2_b, out2bf, out2_b,
        m2w1bf, mlp2_b1, m2w2bf, mlp2_b2);
}